// Round 1
// baseline (568.554 us; speedup 1.0000x reference)
//
#include <hip/hip_runtime.h>
#include <hip/hip_bf16.h>

#define BB 8
#define HH 64
#define WWW 64
#define LL 4096
#define DM 96
#define DI 192
#define RRR 6
#define DHH 32
#define KKK 4
#define NNN 16
#define KRR 24
#define NCH 64
#define TT 64
#define XST 40

__device__ __forceinline__ float softplus_f(float x){
    float ax = fabsf(x);
    return fmaxf(x, 0.f) + __logf(1.f + __expf(-ax));
}
__device__ __forceinline__ float silu_f(float x){ return x / (1.f + __expf(-x)); }

// sequence position t -> spatial index l, per direction k (H=W=64 so pure bit swizzle)
__device__ __forceinline__ int loc_of(int k, int t){
    int tt = (k >= 2) ? (LL - 1 - t) : t;
    if (k & 1) return ((tt & 63) << 6) | (tt >> 6);
    return tt;
}

// ---------------- K0: transpose x_proj_weight (K,38,DI) -> Wt (K,DI,38) ----------------
__global__ void k0_wt(const float* __restrict__ W, float* __restrict__ Wt){
    int i = blockIdx.x * 256 + threadIdx.x;
    if (i >= KKK * 38 * DI) return;
    int k = i / (38 * DI); int rem = i % (38 * DI); int c = rem / DI; int d = rem % DI;
    Wt[(k * DI + d) * 38 + c] = W[i];
}

// ---------------- K1: xw = x @ w_in  (32768 x 96 @ 96 x 192) ----------------
__global__ void k1_inproj(const float* __restrict__ x, const float* __restrict__ w_in,
                          float* __restrict__ xw){
    __shared__ float xL[16][DM];
    int pix0 = blockIdx.x * 16;
    for (int i = threadIdx.x; i < 16 * DM; i += 256){
        int p = i / DM, d = i % DM;
        xL[p][d] = x[(size_t)(pix0 + p) * DM + d];
    }
    __syncthreads();
    for (int e = threadIdx.x; e < 16 * DI; e += 256){
        int p = e / DI, c = e % DI;
        float a = 0.f;
        #pragma unroll 8
        for (int d = 0; d < DM; ++d) a = fmaf(xL[p][d], w_in[d * DI + c], a);
        xw[(size_t)(pix0 + p) * DI + c] = a;
    }
}

// ---------------- K2: xi = silu(dwconv3x3(xw) + b_conv) ----------------
__global__ void k2_conv(const float* __restrict__ xw, const float* __restrict__ wc,
                        const float* __restrict__ bc, float* __restrict__ xi){
    int gid = blockIdx.x * 256 + threadIdx.x;   // BB*LL*48 threads, float4 over channels
    int c4 = gid % 48; int pix = gid / 48;
    int b = pix >> 12; int l = pix & 4095; int h = l >> 6; int w = l & 63;
    int c = c4 * 4;
    float4 acc = *(const float4*)(bc + c);
    #pragma unroll
    for (int dh = 0; dh < 3; ++dh){
        int hh = h + dh - 1; if ((unsigned)hh >= 64u) continue;
        #pragma unroll
        for (int dw = 0; dw < 3; ++dw){
            int ww2 = w + dw - 1; if ((unsigned)ww2 >= 64u) continue;
            float4 tap = *(const float4*)(xw + (size_t)((b << 12) + (hh << 6) + ww2) * DI + c);
            float4 wv  = *(const float4*)(wc + (dh * 3 + dw) * DI + c);
            acc.x = fmaf(tap.x, wv.x, acc.x);
            acc.y = fmaf(tap.y, wv.y, acc.y);
            acc.z = fmaf(tap.z, wv.z, acc.z);
            acc.w = fmaf(tap.w, wv.w, acc.w);
        }
    }
    acc.x = silu_f(acc.x); acc.y = silu_f(acc.y); acc.z = silu_f(acc.z); acc.w = silu_f(acc.w);
    *(float4*)(xi + (size_t)pix * DI + c) = acc;
}

// ---------------- K3: x_dbl[b][k][l][38] = xi[b,l,:] . Wt[k,:,c]  (spatial layout) ----------------
__global__ void k3_proj(const float* __restrict__ xi, const float* __restrict__ Wt,
                        float* __restrict__ xdbl){
    __shared__ float xL[8][DI];
    int pix0 = blockIdx.x * 8;
    for (int i = threadIdx.x; i < 8 * DI; i += 256)
        xL[i / DI][i % DI] = xi[(size_t)pix0 * DI + i];
    __syncthreads();
    int b = pix0 >> 12;
    for (int e = threadIdx.x; e < 8 * KKK * 38; e += 256){
        int p = e / (KKK * 38); int rem = e % (KKK * 38); int k = rem / 38; int c = rem % 38;
        float a = 0.f;
        #pragma unroll 8
        for (int d = 0; d < DI; ++d) a = fmaf(xL[p][d], Wt[(k * DI + d) * 38 + c], a);
        int l = (pix0 + p) & 4095;
        xdbl[((size_t)(b * KKK + k) * LL + l) * XST + c] = a;
    }
}

// ---------------- K4a: per-chunk local scan -> P (decay product), S (local final state) ----------
__global__ void k4a(const float* __restrict__ xi, const float* __restrict__ xdbl,
                    const float* __restrict__ A_logs, const float* __restrict__ dt_bias,
                    float* __restrict__ Pb, float* __restrict__ Sb){
    int chunk = blockIdx.x, k = blockIdx.y, b = blockIdx.z;
    int r = threadIdx.x >> 5, d = threadIdx.x & 31;
    int kr = k * RRR + r;
    float A = -__expf(A_logs[kr]);
    float dtb = dt_bias[kr];
    float h[NNN];
    #pragma unroll
    for (int n = 0; n < NNN; ++n) h[n] = 0.f;
    float P = 1.f;
    const float* xdk = xdbl + (size_t)(b * KKK + k) * LL * XST;
    const float* xib = xi + (size_t)b * LL * DI;
    #pragma unroll 2
    for (int tt = 0; tt < TT; ++tt){
        int t = chunk * TT + tt;
        int loc = loc_of(k, t);
        const float* row = xdk + (size_t)loc * XST;
        float dt = softplus_f(row[r] + dtb);
        float dec = __expf(dt * A);
        float u = xib[(size_t)loc * DI + r * DHH + d];
        float xu = dt * u;
        P *= dec;
        #pragma unroll
        for (int n = 0; n < NNN; ++n) h[n] = fmaf(dec, h[n], xu * row[RRR + n]);
    }
    size_t sb = (((size_t)(b * KRR + kr) * NCH + chunk) * DHH + d) * NNN;
    #pragma unroll
    for (int n = 0; n < NNN; ++n) Sb[sb + n] = h[n];
    if (d == 0) Pb[(size_t)(b * KRR + kr) * NCH + chunk] = P;
}

// ---------------- K4b: cross-chunk exclusive scan (in-place: S becomes h_init per chunk) --------
__global__ void k4b(const float* __restrict__ Pb, float* __restrict__ Sb){
    int scan = blockIdx.x;             // b*KRR + kr
    int tid = threadIdx.x;             // 512 = d*16 + n
    float hb = 0.f;
    size_t base = (size_t)scan * NCH * 512 + tid;
    const float* Pp = Pb + (size_t)scan * NCH;
    for (int c = 0; c < NCH; ++c){
        float s = Sb[base + (size_t)c * 512];
        float p = Pp[c];
        Sb[base + (size_t)c * 512] = hb;
        hb = fmaf(p, hb, s);
    }
}

// ---------------- K4c: replay chunks from h_init, emit y (spatial layout, bf16) ----------------
__global__ void k4c(const float* __restrict__ xi, const float* __restrict__ xdbl,
                    const float* __restrict__ A_logs, const float* __restrict__ dt_bias,
                    const float* __restrict__ Ds, const float* __restrict__ Sb,
                    __hip_bfloat16* __restrict__ ybuf){
    int chunk = blockIdx.x, k = blockIdx.y, b = blockIdx.z;
    int r = threadIdx.x >> 5, d = threadIdx.x & 31;
    int kr = k * RRR + r;
    float A = -__expf(A_logs[kr]);
    float dtb = dt_bias[kr];
    float Dv = Ds[kr * DHH + d];
    float h[NNN];
    size_t sb = (((size_t)(b * KRR + kr) * NCH + chunk) * DHH + d) * NNN;
    #pragma unroll
    for (int n = 0; n < NNN; ++n) h[n] = Sb[sb + n];
    const float* xdk = xdbl + (size_t)(b * KKK + k) * LL * XST;
    const float* xib = xi + (size_t)b * LL * DI;
    __hip_bfloat16* yb = ybuf + (size_t)(k * BB + b) * LL * DI;
    #pragma unroll 2
    for (int tt = 0; tt < TT; ++tt){
        int t = chunk * TT + tt;
        int loc = loc_of(k, t);
        const float* row = xdk + (size_t)loc * XST;
        float dt = softplus_f(row[r] + dtb);
        float dec = __expf(dt * A);
        float u = xib[(size_t)loc * DI + r * DHH + d];
        float xu = dt * u;
        float y = 0.f;
        #pragma unroll
        for (int n = 0; n < NNN; ++n){
            h[n] = fmaf(dec, h[n], xu * row[RRR + n]);
            y = fmaf(h[n], row[RRR + NNN + n], y);
        }
        y = fmaf(u, Dv, y);
        yb[(size_t)loc * DI + r * DHH + d] = __float2bfloat16(y);
    }
}

// ---------------- K5: merge 4 directions + LayerNorm + out-proj ----------------
__global__ void k5_out(const __hip_bfloat16* __restrict__ ybuf, const float* __restrict__ g,
                       const float* __restrict__ bta, const float* __restrict__ w_out,
                       float* __restrict__ out){
    __shared__ float yL[16][DI];
    __shared__ float muL[16], rsL[16];
    int pix0 = blockIdx.x * 16;
    int b = pix0 >> 12;
    int l0 = pix0 & 4095;
    for (int i = threadIdx.x; i < 16 * DI; i += 256){
        int p = i / DI, c = i % DI;
        float s = 0.f;
        #pragma unroll
        for (int k = 0; k < KKK; ++k)
            s += __bfloat162float(ybuf[(size_t)(k * BB + b) * LL * DI + (size_t)(l0 + p) * DI + c]);
        yL[p][c] = s;
    }
    __syncthreads();
    {
        int p = threadIdx.x >> 4, ln = threadIdx.x & 15;
        float s = 0.f, s2 = 0.f;
        for (int c = ln; c < DI; c += 16){ float v = yL[p][c]; s += v; s2 = fmaf(v, v, s2); }
        #pragma unroll
        for (int m = 1; m < 16; m <<= 1){ s += __shfl_xor(s, m, 64); s2 += __shfl_xor(s2, m, 64); }
        if (ln == 0){
            float mu = s * (1.f / DI);
            float var = s2 * (1.f / DI) - mu * mu;
            muL[p] = mu; rsL[p] = rsqrtf(var + 1e-5f);
        }
    }
    __syncthreads();
    for (int i = threadIdx.x; i < 16 * DI; i += 256){
        int p = i / DI, c = i % DI;
        yL[p][c] = (yL[p][c] - muL[p]) * rsL[p] * g[c] + bta[c];
    }
    __syncthreads();
    for (int e = threadIdx.x; e < 16 * DM; e += 256){
        int p = e / DM, m = e % DM;
        float a = 0.f;
        #pragma unroll 8
        for (int c = 0; c < DI; ++c) a = fmaf(yL[p][c], w_out[c * DM + m], a);
        out[(size_t)(pix0 + p) * DM + m] = a;
    }
}

extern "C" void kernel_launch(void* const* d_in, const int* in_sizes, int n_in,
                              void* d_out, int out_size, void* d_ws, size_t ws_size,
                              hipStream_t stream){
    const float* x      = (const float*)d_in[0];
    const float* w_in   = (const float*)d_in[1];
    const float* w_conv = (const float*)d_in[2];
    const float* b_conv = (const float*)d_in[3];
    const float* xproj  = (const float*)d_in[4];
    const float* A_logs = (const float*)d_in[5];
    const float* Ds     = (const float*)d_in[6];
    const float* dtbias = (const float*)d_in[7];
    const float* ln_g   = (const float*)d_in[8];
    const float* ln_b   = (const float*)d_in[9];
    const float* w_out  = (const float*)d_in[10];
    float* out = (float*)d_out;

    // workspace layout (floats):
    // xi 6,291,456 | xdbl 5,242,880 | Pb 16,384 | Sb 6,291,456 | Wt 32,768 |
    // big (union: xw fp32 6,291,456 / ybuf bf16 25,165,824 elems = 12,582,912 floats)
    float* ws   = (float*)d_ws;
    float* xi   = ws;
    float* xdbl = xi + 6291456;
    float* Pb   = xdbl + 5242880;
    float* Sb   = Pb + 16384;
    float* Wt   = Sb + 6291456;
    float* big  = Wt + 32768;
    float* xw   = big;
    __hip_bfloat16* ybuf = (__hip_bfloat16*)big;

    k0_wt<<<114, 256, 0, stream>>>(xproj, Wt);
    k1_inproj<<<2048, 256, 0, stream>>>(x, w_in, xw);
    k2_conv<<<6144, 256, 0, stream>>>(xw, w_conv, b_conv, xi);
    k3_proj<<<4096, 256, 0, stream>>>(xi, Wt, xdbl);
    k4a<<<dim3(NCH, KKK, BB), 192, 0, stream>>>(xi, xdbl, A_logs, dtbias, Pb, Sb);
    k4b<<<192, 512, 0, stream>>>(Pb, Sb);
    k4c<<<dim3(NCH, KKK, BB), 192, 0, stream>>>(xi, xdbl, A_logs, dtbias, Ds, Sb, ybuf);
    k5_out<<<2048, 256, 0, stream>>>(ybuf, ln_g, ln_b, w_out, out);
}

// Round 2
// 304.673 us; speedup vs baseline: 1.8661x; 1.8661x over previous
//
#include <hip/hip_runtime.h>
#include <hip/hip_bf16.h>

#define BB 8
#define LL 4096
#define DM 96
#define DI 192
#define RRR 6
#define DHH 32
#define KKK 4
#define NNN 16
#define KRR 24
#define NCH 64
#define TT 64
#define XKC 160   // padded kc stride: 4 dirs x 40 (dt 0-5, pad 6-7, B 8-23, C 24-39)

__device__ __forceinline__ float softplus_f(float x){
    float ax = fabsf(x);
    return fmaxf(x, 0.f) + __logf(1.f + __expf(-ax));
}
__device__ __forceinline__ float silu_f(float x){ return x / (1.f + __expf(-x)); }

// sequence position t -> spatial index l, per direction k (H=W=64 so pure bit swizzle)
__device__ __forceinline__ int loc_of(int k, int t){
    int tt = (k >= 2) ? (LL - 1 - t) : t;
    if (k & 1) return ((tt & 63) << 6) | (tt >> 6);
    return tt;
}

// ---------------- K0p: prep — Wp[192][160], wg[192][96], sg/bw[96] ----------------
__global__ void k0p(const float* __restrict__ W, const float* __restrict__ g,
                    const float* __restrict__ bta, const float* __restrict__ w_out,
                    float* __restrict__ Wp, float* __restrict__ wg, float* __restrict__ sgbw){
    int i = blockIdx.x * 256 + threadIdx.x;
    if (i < DI * XKC){
        int d = i / XKC, kc = i % XKC; int k = kc / 40, nc = kc % 40;
        float v = 0.f;
        if (nc < 6) v = W[(k * 38 + nc) * DI + d];
        else if (nc >= 8) v = W[(k * 38 + (nc - 2)) * DI + d];
        Wp[i] = v;
    } else if (i < DI * XKC + DI * DM){
        int j = i - DI * XKC; int c = j / DM;
        wg[j] = w_out[j] * g[c];
    } else if (i < DI * XKC + DI * DM + DM){
        int m = i - (DI * XKC + DI * DM);
        float s = 0.f, t = 0.f;
        for (int c = 0; c < DI; ++c){
            float w = w_out[c * DM + m];
            s = fmaf(g[c], w, s);
            t = fmaf(bta[c], w, t);
        }
        sgbw[m] = s; sgbw[DM + m] = t;
    }
}

// ---------------- K1: xw = x @ w_in  (32768 x 96 -> 192), 64-pix blocks ----------------
__global__ __launch_bounds__(384) void k1_inproj(const float* __restrict__ x,
                                                 const float* __restrict__ w_in,
                                                 float* __restrict__ xw){
    __shared__ float xT[DM][68];
    int pix0 = blockIdx.x * 64;
    for (int i = threadIdx.x; i < 64 * DM; i += 384){
        int c = i % DM, p = i / DM;
        xT[c][p] = x[(size_t)(pix0 + p) * DM + c];
    }
    __syncthreads();
    int cg = threadIdx.x % 48, pg = threadIdx.x / 48;   // 8 pixgroups x 48 cgroups
    int p0 = pg * 8;
    float4 acc[8];
    #pragma unroll
    for (int i = 0; i < 8; ++i) acc[i] = make_float4(0.f, 0.f, 0.f, 0.f);
    const float* wcol = w_in + cg * 4;
    for (int d = 0; d < DM; ++d){
        float4 w4 = *(const float4*)(wcol + d * DI);
        float4 xa = *(const float4*)(&xT[d][p0]);
        float4 xb = *(const float4*)(&xT[d][p0 + 4]);
        float xs[8] = {xa.x, xa.y, xa.z, xa.w, xb.x, xb.y, xb.z, xb.w};
        #pragma unroll
        for (int pi = 0; pi < 8; ++pi){
            acc[pi].x = fmaf(xs[pi], w4.x, acc[pi].x);
            acc[pi].y = fmaf(xs[pi], w4.y, acc[pi].y);
            acc[pi].z = fmaf(xs[pi], w4.z, acc[pi].z);
            acc[pi].w = fmaf(xs[pi], w4.w, acc[pi].w);
        }
    }
    #pragma unroll
    for (int pi = 0; pi < 8; ++pi)
        *(float4*)(xw + (size_t)(pix0 + p0 + pi) * DI + cg * 4) = acc[pi];
}

// ---------------- K2: xi = silu(dwconv3x3(xw) + b_conv) ----------------
__global__ void k2_conv(const float* __restrict__ xw, const float* __restrict__ wc,
                        const float* __restrict__ bc, float* __restrict__ xi){
    int gid = blockIdx.x * 256 + threadIdx.x;   // BB*LL*48 threads, float4 over channels
    int c4 = gid % 48; int pix = gid / 48;
    int b = pix >> 12; int l = pix & 4095; int h = l >> 6; int w = l & 63;
    int c = c4 * 4;
    float4 acc = *(const float4*)(bc + c);
    #pragma unroll
    for (int dh = 0; dh < 3; ++dh){
        int hh = h + dh - 1; if ((unsigned)hh >= 64u) continue;
        #pragma unroll
        for (int dw = 0; dw < 3; ++dw){
            int ww2 = w + dw - 1; if ((unsigned)ww2 >= 64u) continue;
            float4 tap = *(const float4*)(xw + (size_t)((b << 12) + (hh << 6) + ww2) * DI + c);
            float4 wv  = *(const float4*)(wc + (dh * 3 + dw) * DI + c);
            acc.x = fmaf(tap.x, wv.x, acc.x);
            acc.y = fmaf(tap.y, wv.y, acc.y);
            acc.z = fmaf(tap.z, wv.z, acc.z);
            acc.w = fmaf(tap.w, wv.w, acc.w);
        }
    }
    acc.x = silu_f(acc.x); acc.y = silu_f(acc.y); acc.z = silu_f(acc.z); acc.w = silu_f(acc.w);
    *(float4*)(xi + (size_t)pix * DI + c) = acc;
}

// ---------------- K3: xdbl[pix][160] = xi[pix][:] @ Wp  (64-pix blocks) ----------------
__global__ __launch_bounds__(320) void k3_proj(const float* __restrict__ xi,
                                               const float* __restrict__ Wp,
                                               float* __restrict__ xdbl){
    __shared__ float xT[DI][68];
    int pix0 = blockIdx.x * 64;
    for (int i = threadIdx.x; i < 64 * DI; i += 320){
        int c = i % DI, p = i / DI;
        xT[c][p] = xi[(size_t)(pix0 + p) * DI + c];
    }
    __syncthreads();
    int kg = threadIdx.x % 40, pg = threadIdx.x / 40;   // 8 pixgroups x 40 kcgroups
    int p0 = pg * 8;
    float4 acc[8];
    #pragma unroll
    for (int i = 0; i < 8; ++i) acc[i] = make_float4(0.f, 0.f, 0.f, 0.f);
    const float* wcol = Wp + kg * 4;
    for (int d = 0; d < DI; ++d){
        float4 w4 = *(const float4*)(wcol + d * XKC);
        float4 xa = *(const float4*)(&xT[d][p0]);
        float4 xb = *(const float4*)(&xT[d][p0 + 4]);
        float xs[8] = {xa.x, xa.y, xa.z, xa.w, xb.x, xb.y, xb.z, xb.w};
        #pragma unroll
        for (int pi = 0; pi < 8; ++pi){
            acc[pi].x = fmaf(xs[pi], w4.x, acc[pi].x);
            acc[pi].y = fmaf(xs[pi], w4.y, acc[pi].y);
            acc[pi].z = fmaf(xs[pi], w4.z, acc[pi].z);
            acc[pi].w = fmaf(xs[pi], w4.w, acc[pi].w);
        }
    }
    #pragma unroll
    for (int pi = 0; pi < 8; ++pi)
        *(float4*)(xdbl + (size_t)(pix0 + p0 + pi) * XKC + kg * 4) = acc[pi];
}

// ---------------- K4a: per-chunk local scan -> P (decay product), S (local final state) ----------
__global__ __launch_bounds__(192) void k4a(const float* __restrict__ xi, const float* __restrict__ xdbl,
                    const float* __restrict__ A_logs, const float* __restrict__ dt_bias,
                    float* __restrict__ Pb, float* __restrict__ Sb){
    int chunk = blockIdx.x, k = blockIdx.y, b = blockIdx.z;
    int r = threadIdx.x >> 5, d = threadIdx.x & 31;
    int kr = k * RRR + r;
    float A = -__expf(A_logs[kr]);
    float dtb = dt_bias[kr];
    float h[NNN];
    #pragma unroll
    for (int n = 0; n < NNN; ++n) h[n] = 0.f;
    float P = 1.f;
    const float* xd = xdbl + ((size_t)b << 12) * XKC + k * 40;
    const float* xib = xi + ((size_t)b << 12) * DI + r * DHH + d;
    #pragma unroll 2
    for (int tt = 0; tt < TT; ++tt){
        int t = chunk * TT + tt;
        int loc = loc_of(k, t);
        const float* row = xd + (size_t)loc * XKC;
        float dt = softplus_f(row[r] + dtb);
        float dec = __expf(dt * A);
        float u = xib[(size_t)loc * DI];
        float xu = dt * u;
        P *= dec;
        float Bv[NNN];
        *(float4*)(Bv + 0)  = *(const float4*)(row + 8);
        *(float4*)(Bv + 4)  = *(const float4*)(row + 12);
        *(float4*)(Bv + 8)  = *(const float4*)(row + 16);
        *(float4*)(Bv + 12) = *(const float4*)(row + 20);
        #pragma unroll
        for (int n = 0; n < NNN; ++n) h[n] = fmaf(dec, h[n], xu * Bv[n]);
    }
    size_t sb = (((size_t)(b * KRR + kr) * NCH + chunk) * DHH + d) * NNN;
    #pragma unroll
    for (int n = 0; n < NNN; ++n) Sb[sb + n] = h[n];
    if (d == 0) Pb[(size_t)(b * KRR + kr) * NCH + chunk] = P;
}

// ---------------- K4b: cross-chunk exclusive scan (in-place: S becomes h_init per chunk) --------
__global__ __launch_bounds__(512) void k4b(const float* __restrict__ Pb, float* __restrict__ Sb){
    int scan = blockIdx.x;             // b*KRR + kr
    int tid = threadIdx.x;             // 512 = d*16 + n
    size_t base = (size_t)scan * NCH * 512 + tid;
    const float* Pp = Pb + (size_t)scan * NCH;
    float s[NCH];
    #pragma unroll
    for (int c = 0; c < NCH; ++c) s[c] = Sb[base + (size_t)c * 512];
    float hb = 0.f;
    #pragma unroll
    for (int c = 0; c < NCH; ++c){
        float nv = fmaf(Pp[c], hb, s[c]);
        Sb[base + (size_t)c * 512] = hb;
        hb = nv;
    }
}

// ---------------- K4c: replay chunks from h_init, emit y (spatial layout, bf16) ----------------
__global__ __launch_bounds__(192) void k4c(const float* __restrict__ xi, const float* __restrict__ xdbl,
                    const float* __restrict__ A_logs, const float* __restrict__ dt_bias,
                    const float* __restrict__ Ds, const float* __restrict__ Sb,
                    __hip_bfloat16* __restrict__ ybuf){
    int chunk = blockIdx.x, k = blockIdx.y, b = blockIdx.z;
    int r = threadIdx.x >> 5, d = threadIdx.x & 31;
    int kr = k * RRR + r;
    float A = -__expf(A_logs[kr]);
    float dtb = dt_bias[kr];
    float Dv = Ds[kr * DHH + d];
    float h[NNN];
    size_t sb = (((size_t)(b * KRR + kr) * NCH + chunk) * DHH + d) * NNN;
    #pragma unroll
    for (int n = 0; n < NNN; ++n) h[n] = Sb[sb + n];
    const float* xd = xdbl + ((size_t)b << 12) * XKC + k * 40;
    const float* xib = xi + ((size_t)b << 12) * DI + r * DHH + d;
    __hip_bfloat16* yb = ybuf + (size_t)(k * BB + b) * LL * DI + r * DHH + d;
    #pragma unroll 2
    for (int tt = 0; tt < TT; ++tt){
        int t = chunk * TT + tt;
        int loc = loc_of(k, t);
        const float* row = xd + (size_t)loc * XKC;
        float dt = softplus_f(row[r] + dtb);
        float dec = __expf(dt * A);
        float u = xib[(size_t)loc * DI];
        float xu = dt * u;
        float Bv[NNN], Cv[NNN];
        *(float4*)(Bv + 0)  = *(const float4*)(row + 8);
        *(float4*)(Bv + 4)  = *(const float4*)(row + 12);
        *(float4*)(Bv + 8)  = *(const float4*)(row + 16);
        *(float4*)(Bv + 12) = *(const float4*)(row + 20);
        *(float4*)(Cv + 0)  = *(const float4*)(row + 24);
        *(float4*)(Cv + 4)  = *(const float4*)(row + 28);
        *(float4*)(Cv + 8)  = *(const float4*)(row + 32);
        *(float4*)(Cv + 12) = *(const float4*)(row + 36);
        float y = 0.f;
        #pragma unroll
        for (int n = 0; n < NNN; ++n){
            h[n] = fmaf(dec, h[n], xu * Bv[n]);
            y = fmaf(h[n], Cv[n], y);
        }
        y = fmaf(u, Dv, y);
        yb[(size_t)loc * DI] = __float2bfloat16(y);
    }
}

// ---------------- K5: merge 4 directions + fused LayerNorm + out-proj ----------------
__global__ __launch_bounds__(256) void k5_out(const __hip_bfloat16* __restrict__ ybuf,
                       const float* __restrict__ wg, const float* __restrict__ sgbw,
                       float* __restrict__ out){
    __shared__ float yT[DI][36];
    __shared__ float rsL[32], rmL[32];
    int pix0 = blockIdx.x * 32;
    int b = pix0 >> 12;
    int l0 = pix0 & 4095;
    const size_t kstride = (size_t)BB * LL * DI;
    for (int i = threadIdx.x; i < 32 * DI; i += 256){
        int c = i % DI, p = i / DI;
        size_t off = (size_t)b * LL * DI + (size_t)(l0 + p) * DI + c;
        float s = __bfloat162float(ybuf[off])
                + __bfloat162float(ybuf[off + kstride])
                + __bfloat162float(ybuf[off + 2 * kstride])
                + __bfloat162float(ybuf[off + 3 * kstride]);
        yT[c][p] = s;
    }
    __syncthreads();
    {
        int p = threadIdx.x >> 3, cg = threadIdx.x & 7;
        float s = 0.f, s2 = 0.f;
        for (int c = cg; c < DI; c += 8){ float v = yT[c][p]; s += v; s2 = fmaf(v, v, s2); }
        s += __shfl_xor(s, 1, 64); s2 += __shfl_xor(s2, 1, 64);
        s += __shfl_xor(s, 2, 64); s2 += __shfl_xor(s2, 2, 64);
        s += __shfl_xor(s, 4, 64); s2 += __shfl_xor(s2, 4, 64);
        if (cg == 0){
            float mu = s * (1.f / DI);
            float var = s2 * (1.f / DI) - mu * mu;
            float rs = rsqrtf(var + 1e-5f);
            rsL[p] = rs; rmL[p] = rs * mu;
        }
    }
    __syncthreads();
    if (threadIdx.x < 192){
        int mg = threadIdx.x % 24, pg = threadIdx.x / 24;  // 8 pixgroups x 24 mgroups
        int p0 = pg * 4;
        float4 acc[4];
        #pragma unroll
        for (int i = 0; i < 4; ++i) acc[i] = make_float4(0.f, 0.f, 0.f, 0.f);
        const float* wcol = wg + mg * 4;
        for (int c = 0; c < DI; ++c){
            float4 w4 = *(const float4*)(wcol + c * DM);
            float4 yv = *(const float4*)(&yT[c][p0]);
            float ys[4] = {yv.x, yv.y, yv.z, yv.w};
            #pragma unroll
            for (int pi = 0; pi < 4; ++pi){
                acc[pi].x = fmaf(ys[pi], w4.x, acc[pi].x);
                acc[pi].y = fmaf(ys[pi], w4.y, acc[pi].y);
                acc[pi].z = fmaf(ys[pi], w4.z, acc[pi].z);
                acc[pi].w = fmaf(ys[pi], w4.w, acc[pi].w);
            }
        }
        float4 sg4 = *(const float4*)(sgbw + mg * 4);
        float4 bw4 = *(const float4*)(sgbw + DM + mg * 4);
        #pragma unroll
        for (int pi = 0; pi < 4; ++pi){
            float rs = rsL[p0 + pi], rm = rmL[p0 + pi];
            float4 o;
            o.x = fmaf(acc[pi].x, rs, fmaf(-rm, sg4.x, bw4.x));
            o.y = fmaf(acc[pi].y, rs, fmaf(-rm, sg4.y, bw4.y));
            o.z = fmaf(acc[pi].z, rs, fmaf(-rm, sg4.z, bw4.z));
            o.w = fmaf(acc[pi].w, rs, fmaf(-rm, sg4.w, bw4.w));
            *(float4*)(out + (size_t)(pix0 + p0 + pi) * DM + mg * 4) = o;
        }
    }
}

extern "C" void kernel_launch(void* const* d_in, const int* in_sizes, int n_in,
                              void* d_out, int out_size, void* d_ws, size_t ws_size,
                              hipStream_t stream){
    const float* x      = (const float*)d_in[0];
    const float* w_in   = (const float*)d_in[1];
    const float* w_conv = (const float*)d_in[2];
    const float* b_conv = (const float*)d_in[3];
    const float* xproj  = (const float*)d_in[4];
    const float* A_logs = (const float*)d_in[5];
    const float* Ds     = (const float*)d_in[6];
    const float* dtbias = (const float*)d_in[7];
    const float* ln_g   = (const float*)d_in[8];
    const float* ln_b   = (const float*)d_in[9];
    const float* w_out  = (const float*)d_in[10];
    float* out = (float*)d_out;

    // workspace layout (floats):
    float* ws   = (float*)d_ws;
    float* xi   = ws;                      // 6,291,456
    float* xdbl = xi + 6291456;            // 32768*160 = 5,242,880
    float* Pb   = xdbl + 5242880;          // 16,384
    float* Sb   = Pb + 16384;              // 6,291,456
    float* Wp   = Sb + 6291456;            // 192*160 = 30,720
    float* wg   = Wp + 30720;              // 192*96  = 18,432
    float* sgbw = wg + 18432;              // 192
    float* big  = sgbw + 192;              // union: xw fp32 (6,291,456) / ybuf bf16 (12,582,912 f-equiv)
    float* xw   = big;
    __hip_bfloat16* ybuf = (__hip_bfloat16*)big;

    k0p<<<193, 256, 0, stream>>>(xproj, ln_g, ln_b, w_out, Wp, wg, sgbw);
    k1_inproj<<<512, 384, 0, stream>>>(x, w_in, xw);
    k2_conv<<<6144, 256, 0, stream>>>(xw, w_conv, b_conv, xi);
    k3_proj<<<512, 320, 0, stream>>>(xi, Wp, xdbl);
    k4a<<<dim3(NCH, KKK, BB), 192, 0, stream>>>(xi, xdbl, A_logs, dtbias, Pb, Sb);
    k4b<<<192, 512, 0, stream>>>(Pb, Sb);
    k4c<<<dim3(NCH, KKK, BB), 192, 0, stream>>>(xi, xdbl, A_logs, dtbias, Ds, Sb, ybuf);
    k5_out<<<1024, 256, 0, stream>>>(ybuf, wg, sgbw, out);
}